// Round 2
// 308.374 us; speedup vs baseline: 1.0514x; 1.0514x over previous
//
#include <hip/hip_runtime.h>

#define NN 2048
#define EPS 0.01f
#define ROWS 8            // rows of W per block
#define BLOCKS_PER_B 256  // 2048 / 8
#define NBLK (8 * BLOCKS_PER_B)  // 2048 blocks

// Native clang vector type: __builtin_nontemporal_load requires a pointer
// to scalar/vector-of-scalar, not HIP_vector_type<float,4>.
typedef float f32x4 __attribute__((ext_vector_type(4)));

// Stage 1: 2048 blocks (256/batch), 256 threads. Register-only pred
// comparands. All 16 W float4 loads are issued NONTEMPORAL (no cache
// allocation -> no dirty-victim evictions against the 1 GiB poison fill
// that immediately precedes this dispatch every timed iteration) and
// hoisted up front for 16-deep MLP per wave. Wave shuffle reduce, one
// plain float store per block into d_ws (no same-address atomics).
__global__ __launch_bounds__(256, 4) void coloring_loss_stage1(
    const float* __restrict__ W,
    const float* __restrict__ pred,
    float* __restrict__ partial)
{
    __shared__ float s_partial[4];  // 4 waves

    const int bid  = blockIdx.x;
    const int b    = bid >> 8;               // bid / 256
    const int row0 = (bid & 255) * ROWS;     // first row this block owns
    const int t    = threadIdx.x;

    const float* predb = pred + (size_t)b * NN;

    // This thread's 8 comparand pred_j values -> registers (L1/L2 hits).
    const f32x4 pj0 = ((const f32x4*)predb)[t];
    const f32x4 pj1 = ((const f32x4*)predb)[t + 256];

    // Row-anchor pred_i values: block-uniform addresses -> scalar loads.
    float pis[ROWS];
#pragma unroll
    for (int r = 0; r < ROWS; ++r) pis[r] = predb[row0 + r];

    // W[b, 1, row0, :] base.
    const float* wbase = W + (((size_t)b * 2 + 1) * (size_t)NN + (size_t)row0) * (size_t)NN;

    // Issue ALL 16 nontemporal float4 loads before consuming anything:
    // maximal per-wave MLP, zero cache allocation. ~110 VGPRs live, fits
    // the 128-VGPR budget of __launch_bounds__(256,4).
    f32x4 w0[ROWS], w1[ROWS];
#pragma unroll
    for (int r = 0; r < ROWS; ++r) {
        const f32x4* w4 = (const f32x4*)(wbase + (size_t)r * NN);
        w0[r] = __builtin_nontemporal_load(w4 + t);
        w1[r] = __builtin_nontemporal_load(w4 + t + 256);
    }

    int cnt = 0;
#pragma unroll
    for (int r = 0; r < ROWS; ++r) {
        const float pi = pis[r];
        const f32x4 a = w0[r];
        const f32x4 c = w1[r];
        cnt += (a.x == 1.0f) && (fabsf(pi - pj0.x) < EPS);
        cnt += (a.y == 1.0f) && (fabsf(pi - pj0.y) < EPS);
        cnt += (a.z == 1.0f) && (fabsf(pi - pj0.z) < EPS);
        cnt += (a.w == 1.0f) && (fabsf(pi - pj0.w) < EPS);
        cnt += (c.x == 1.0f) && (fabsf(pi - pj1.x) < EPS);
        cnt += (c.y == 1.0f) && (fabsf(pi - pj1.y) < EPS);
        cnt += (c.z == 1.0f) && (fabsf(pi - pj1.z) < EPS);
        cnt += (c.w == 1.0f) && (fabsf(pi - pj1.w) < EPS);
    }

    // Wave (64-lane) shuffle reduction.
#pragma unroll
    for (int off = 32; off > 0; off >>= 1)
        cnt += __shfl_down(cnt, off, 64);

    const int wave = t >> 6;
    const int lane = t & 63;
    if (lane == 0) s_partial[wave] = (float)cnt;
    __syncthreads();

    if (t == 0) {
        partial[bid] = s_partial[0] + s_partial[1] + s_partial[2] + s_partial[3];
    }
}

// Stage 2: one block reduces the 2048 partials -> out[0]. Overwrites out
// unconditionally (d_out is poisoned 0xAA before every timed launch).
__global__ __launch_bounds__(256) void coloring_loss_stage2(
    const float* __restrict__ partial,
    float* __restrict__ out)
{
    __shared__ float s_partial[4];
    const int t = threadIdx.x;

    const f32x4* p4 = (const f32x4*)partial;  // 2048 floats = 512 float4
    const f32x4 a = p4[t];
    const f32x4 c = p4[t + 256];
    float s = a.x + a.y + a.z + a.w + c.x + c.y + c.z + c.w;

#pragma unroll
    for (int off = 32; off > 0; off >>= 1)
        s += __shfl_down(s, off, 64);

    const int wave = t >> 6;
    const int lane = t & 63;
    if (lane == 0) s_partial[wave] = s;
    __syncthreads();

    if (t == 0)
        out[0] = s_partial[0] + s_partial[1] + s_partial[2] + s_partial[3];
}

extern "C" void kernel_launch(void* const* d_in, const int* in_sizes, int n_in,
                              void* d_out, int out_size, void* d_ws, size_t ws_size,
                              hipStream_t stream) {
    const float* W    = (const float*)d_in[0];  // (8, 2, 2048, 2048) f32
    const float* pred = (const float*)d_in[1];  // (8, 2048) f32
    // d_in[2] (tgt) unused by the loss.
    float* out     = (float*)d_out;
    float* partial = (float*)d_ws;  // 2048 floats of scratch

    coloring_loss_stage1<<<NBLK, 256, 0, stream>>>(W, pred, partial);
    coloring_loss_stage2<<<1, 256, 0, stream>>>(partial, out);
}